// Round 7
// baseline (375.615 us; speedup 1.0000x reference)
//
#include <hip/hip_runtime.h>
#include <math.h>

#define T_SEQ 1024
#define C_DIM 2048
#define H_NUM 16
#define D_HEAD 128
#define BT 4096              // B*T rows
#define QKV_N 6144           // 3*C

typedef __bf16 bf16x8 __attribute__((ext_vector_type(8)));
typedef float f32x4 __attribute__((ext_vector_type(4)));
typedef unsigned short u16;
typedef unsigned int u32;

#define AS1C(p) ((const __attribute__((address_space(1))) void*)(p))
#define AS3(p)  ((__attribute__((address_space(3))) void*)(p))

__device__ __forceinline__ u16 f2bf(float f) {
    u32 u = __builtin_bit_cast(u32, f);
    u += 0x7fffu + ((u >> 16) & 1u);          // RNE
    return (u16)(u >> 16);
}
__device__ __forceinline__ void unpack8(uint4 u, float* f) {
    const u32 w0 = u.x, w1 = u.y, w2 = u.z, w3 = u.w;
    f[0] = __builtin_bit_cast(float, w0 << 16);
    f[1] = __builtin_bit_cast(float, w0 & 0xffff0000u);
    f[2] = __builtin_bit_cast(float, w1 << 16);
    f[3] = __builtin_bit_cast(float, w1 & 0xffff0000u);
    f[4] = __builtin_bit_cast(float, w2 << 16);
    f[5] = __builtin_bit_cast(float, w2 & 0xffff0000u);
    f[6] = __builtin_bit_cast(float, w3 << 16);
    f[7] = __builtin_bit_cast(float, w3 & 0xffff0000u);
}
__device__ __forceinline__ uint4 pack8(const float* f) {
    uint4 u;
    u.x = (u32)f2bf(f[0]) | ((u32)f2bf(f[1]) << 16);
    u.y = (u32)f2bf(f[2]) | ((u32)f2bf(f[3]) << 16);
    u.z = (u32)f2bf(f[4]) | ((u32)f2bf(f[5]) << 16);
    u.w = (u32)f2bf(f[6]) | ((u32)f2bf(f[7]) << 16);
    return u;
}

__device__ __forceinline__ void ph_barrier() {
    asm volatile("" ::: "memory");
    __builtin_amdgcn_s_barrier();
    asm volatile("" ::: "memory");
}

// ---------------------------------------------------------------------------
// Elementwise fp32 -> bf16 cast (x -> xb).
// ---------------------------------------------------------------------------
__global__ __launch_bounds__(256) void cast_bf16(
    const float* __restrict__ in, u16* __restrict__ out)
{
    int i = blockIdx.x * 256 + threadIdx.x;
    float4 v = ((const float4*)in)[i];
    ushort4 o;
    o.x = f2bf(v.x); o.y = f2bf(v.y); o.z = f2bf(v.z); o.w = f2bf(v.w);
    ((ushort4*)out)[i] = o;
}

// ---------------------------------------------------------------------------
// fp32 [R][Cc] -> bf16 [Cc][R] transpose+cast. 32x32 tile, 256 threads.
// ---------------------------------------------------------------------------
__global__ __launch_bounds__(256) void transpose_cast(
    const float* __restrict__ in, u16* __restrict__ out, int R, int Cc)
{
    __shared__ float tile[32][33];
    const int c0 = blockIdx.x * 32, r0 = blockIdx.y * 32;
    const int tx = threadIdx.x & 31, ty = threadIdx.x >> 5;  // ty 0..7
#pragma unroll
    for (int i = 0; i < 32; i += 8)
        tile[ty + i][tx] = in[(size_t)(r0 + ty + i) * Cc + c0 + tx];
    __syncthreads();
#pragma unroll
    for (int i = 0; i < 32; i += 8)
        out[(size_t)(c0 + ty + i) * R + r0 + tx] = f2bf(tile[tx][ty + i]);
}

// ---------------------------------------------------------------------------
// 128x128-tile BK=32 8-wave MFMA GEMM, THREE BLOCKS PER CU (round-7).
// Extends r6's proven lever (cross-block MFMA/LDS overlap, m114): LDS cut to
// 32 KB/block (2 bufs x [A 8K | B 8K]) -> 3 blocks/CU, 24 waves/CU (6/SIMD).
// __launch_bounds__(512,6) caps VGPR at 85 (acc = 32 VGPR).
// Waves 2M x 4N: per-wave 64x32 = 4 mt x 2 nt, 8 MFMA/kt (single K-slice).
// Schedule = r2/r6-proven relaxed 2-phase, ledger re-derived for 1-issue
// stages:
//   ph1: read cb.B(2)+cb.A mt01(2); stage A(kt+1)->nb  [nb.A readers
//        retired at (kt-1) BARRIER_B]; MFMA mt01; BARRIER_A [all cb.B
//        reads have in-ph1 MFMA consumers -> drained].
//   ph2: read cb.A mt23(2) (in-ph2 consumers); stage B(kt+2)->cb.B
//        [readers retired at BARRIER_A]; MFMA mt23;
//        FIFO at end of kt = [B(kt+1), A(kt+1), B(kt+2)] -> vmcnt(1)
//        drains kt+1 fully, leaves B(kt+2) in flight. Tail: vmcnt(0).
// Swizzle (rule 21, 4-slot/64B rows): phys slot = logical ^ ((row>>1)&3):
// 16 rows/ds_read spread over 8 bank-groups x 2 lanes = 2-way = free.
// Stage source pre-XOR: sslot = (lane&3) ^ ((lane>>3)&3)  [=(row>>1)&3].
// Read slot: sl = (l4 ^ ((l15>>1)&3))*16  [row parity term = (l15>>1)&3].
// ---------------------------------------------------------------------------
template <int OUT_BF16>
__global__ __launch_bounds__(512, 6) void gemm_bf16_q32(
    const u16* __restrict__ A,    // [M][K] bf16
    const u16* __restrict__ Bt,   // [N][K] bf16 (B transposed)
    const float* __restrict__ bias,
    void* __restrict__ Cout,      // bf16 [M][N] or fp32 [M][N]
    int M, int N, int K)
{
    __shared__ alignas(16) char lds[2][16384];   // [buf][A 8K | B 8K]

    const int tid  = threadIdx.x;
    const int lane = tid & 63;
    const int w    = tid >> 6;      // 0..7
    const int wr   = w >> 2;        // 0..1 (M)
    const int wc   = w & 3;         // 0..3 (N)
    const int l15  = lane & 15;
    const int l4   = lane >> 4;
    const int m0   = blockIdx.y * 128;
    const int n0   = blockIdx.x * 128;
    const int NT   = K >> 5;        // K-tiles of 32

    f32x4 acc[4][2] = {};

    // staging: dest linear (wave base + lane*16); row = w*16 + (lane>>2),
    // phys slot = lane&3; source slot pre-XOR'd with (row>>1)&3.
    const int srow  = w * 16 + (lane >> 2);
    const int sslot = (lane & 3) ^ ((lane >> 3) & 3);
    const size_t aoff = (size_t)(m0 + srow) * K + sslot * 8;
    const size_t boff = (size_t)(n0 + srow) * K + sslot * 8;

    auto stageA = [&](char* buf, int k0) {       // 128 rows x 64B, 1 issue
        __builtin_amdgcn_global_load_lds(AS1C(A + aoff + k0),
                                         AS3(buf + w * 1024), 16, 0, 0);
    };
    auto stageB = [&](char* buf, int k0) {
        __builtin_amdgcn_global_load_lds(AS1C(Bt + boff + k0),
                                         AS3(buf + 8192 + w * 1024), 16, 0, 0);
    };

    // prologue: kt0 {B,A} -> buf0; kt1 {B} -> buf1. FIFO [B0,A0,B1]:
    // vmcnt(1) drains kt0, leaves B1 in flight.
    stageB(lds[0], 0);
    stageA(lds[0], 0);
    stageB(lds[1], 32);
    asm volatile("s_waitcnt vmcnt(1)" ::: "memory");
    ph_barrier();

    const int sl   = (l4 ^ ((l15 >> 1) & 3)) << 4;
    const int arow = (wr * 64 + l15) * 64;             // + mt*1024
    const int brow = 8192 + (wc * 32 + l15) * 64;      // + nt*1024

    for (int kt = 0; kt < NT; ++kt) {
        char* cb = lds[kt & 1];
        char* nb = lds[(kt & 1) ^ 1];

        // ---- ph1: read B(2)+A mt01(2); stage A(kt+1)->nb; MFMA mt01 ------
        bf16x8 bfr[2], af[2];
        bfr[0] = __builtin_bit_cast(bf16x8, *(const uint4*)(cb + brow + sl));
        bfr[1] = __builtin_bit_cast(bf16x8, *(const uint4*)(cb + brow + 1024 + sl));
        af[0]  = __builtin_bit_cast(bf16x8, *(const uint4*)(cb + arow + sl));
        af[1]  = __builtin_bit_cast(bf16x8, *(const uint4*)(cb + arow + 1024 + sl));
        if (kt + 1 < NT) stageA(nb, (kt + 1) << 5);
        __builtin_amdgcn_s_setprio(1);
#pragma unroll
        for (int mt = 0; mt < 2; ++mt)
#pragma unroll
            for (int nt = 0; nt < 2; ++nt)
                acc[mt][nt] = __builtin_amdgcn_mfma_f32_16x16x32_bf16(
                    af[mt], bfr[nt], acc[mt][nt], 0, 0, 0);
        __builtin_amdgcn_s_setprio(0);
        ph_barrier();                       // BARRIER_A

        // ---- ph2: read A mt23(2); stage B(kt+2)->cb.B; MFMA mt23 ---------
        bf16x8 ag[2];
        ag[0] = __builtin_bit_cast(bf16x8, *(const uint4*)(cb + arow + 2048 + sl));
        ag[1] = __builtin_bit_cast(bf16x8, *(const uint4*)(cb + arow + 3072 + sl));
        if (kt + 2 < NT) stageB(cb, (kt + 2) << 5);
        __builtin_amdgcn_s_setprio(1);
#pragma unroll
        for (int mt = 0; mt < 2; ++mt)
#pragma unroll
            for (int nt = 0; nt < 2; ++nt)
                acc[mt + 2][nt] = __builtin_amdgcn_mfma_f32_16x16x32_bf16(
                    ag[mt], bfr[nt], acc[mt + 2][nt], 0, 0, 0);
        __builtin_amdgcn_s_setprio(0);
        if (kt < NT - 2)
            asm volatile("s_waitcnt vmcnt(1)" ::: "memory");
        else
            asm volatile("s_waitcnt vmcnt(0)" ::: "memory");
        ph_barrier();                       // BARRIER_B
    }

    // epilogue: C/D layout row=l4*4+reg, col=l15
#pragma unroll
    for (int nt = 0; nt < 2; ++nt) {
        const int colg = n0 + wc * 32 + nt * 16 + l15;
        const float bv = bias[colg];
#pragma unroll
        for (int mt = 0; mt < 4; ++mt) {
            const int rowb = m0 + wr * 64 + mt * 16 + l4 * 4;
#pragma unroll
            for (int r = 0; r < 4; ++r) {
                const float v = acc[mt][nt][r] + bv;
                if (OUT_BF16)
                    ((u16*)Cout)[(size_t)(rowb + r) * N + colg] = f2bf(v);
                else
                    ((float*)Cout)[(size_t)(rowb + r) * N + colg] = v;
            }
        }
    }
}

// ---------------------------------------------------------------------------
// 128xBN-tile 8-wave MFMA GEMM, 2 blocks/CU (r6-proven; kept for proj).
// ---------------------------------------------------------------------------
template <int BN, int OUT_BF16>
__global__ __launch_bounds__(512, 4) void gemm_bf16_ov(
    const u16* __restrict__ A,    // [M][K] bf16
    const u16* __restrict__ Bt,   // [N][K] bf16 (B transposed)
    const float* __restrict__ bias,
    void* __restrict__ Cout,      // bf16 [M][N] or fp32 [M][N]
    int M, int N, int K)
{
    constexpr int BI  = BN / 64;         // B stage issues per wave
    constexpr int NTW = BN / 64;         // n-frags per wave
    constexpr int WCOLS = BN / 4;        // cols per wave
    __shared__ alignas(16) char lds[2][16384 + BN * 128];  // [buf][A 16K | B]

    const int tid  = threadIdx.x;
    const int lane = tid & 63;
    const int w    = tid >> 6;      // 0..7
    const int wr   = w >> 2;        // 0..1 (M)
    const int wc   = w & 3;         // 0..3 (N)
    const int l15  = lane & 15;
    const int l4   = lane >> 4;
    const int m0   = blockIdx.y * 128;
    const int n0   = blockIdx.x * BN;
    const int NT   = K >> 6;        // K-tiles of 64

    f32x4 acc[4][NTW] = {};

    const int srow  = w * 16 + (lane >> 3);          // A rows, +i*8 per issue
    const int sslot = (lane & 7) ^ (lane >> 3);      // row&7 == lane>>3
    const size_t aoff = (size_t)(m0 + srow) * K + sslot * 8;
    const int brow_s = w * 8 + (lane >> 3);          // B rows, +i*64 per issue
    const size_t boff = (size_t)(n0 + brow_s) * K + sslot * 8;

    auto stageA = [&](char* buf, int k0) {           // 128 rows, 2 issues
#pragma unroll
        for (int i = 0; i < 2; ++i)
            __builtin_amdgcn_global_load_lds(
                AS1C(A + aoff + (size_t)(i * 8) * K + k0),
                AS3(buf + w * 2048 + i * 1024), 16, 0, 0);
    };
    auto stageB = [&](char* buf, int k0) {           // BN rows, BI issues
#pragma unroll
        for (int i = 0; i < BI; ++i)
            __builtin_amdgcn_global_load_lds(
                AS1C(Bt + boff + (size_t)(i * 64) * K + k0),
                AS3(buf + 16384 + i * 8192 + w * 1024), 16, 0, 0);
    };

    // prologue: B(kt0), A(kt0) -> buf0; B(kt1) -> buf1.
    stageB(lds[0], 0);
    stageA(lds[0], 0);
    stageB(lds[1], 64);
    if (BI == 3) asm volatile("s_waitcnt vmcnt(3)" ::: "memory");
    else         asm volatile("s_waitcnt vmcnt(2)" ::: "memory");
    ph_barrier();

    const int sl0  = (l4 ^ (l15 & 7)) << 4;
    const int sl1  = sl0 ^ 64;
    const int arow = (wr * 64 + l15) * 128;
    const int brow = 16384 + (wc * WCOLS + l15) * 128;

    for (int kt = 0; kt < NT; ++kt) {
        char* cb = lds[kt & 1];
        char* nb = lds[(kt & 1) ^ 1];

        // ---- phase 1: read B(all)+A mt01, stage (kt+1):A, MFMA mt01 ------
        bf16x8 bfr[NTW][2], af[2][2];
#pragma unroll
        for (int nt = 0; nt < NTW; ++nt) {
            bfr[nt][0] = __builtin_bit_cast(bf16x8,
                *(const uint4*)(cb + brow + nt * 2048 + sl0));
            bfr[nt][1] = __builtin_bit_cast(bf16x8,
                *(const uint4*)(cb + brow + nt * 2048 + sl1));
        }
#pragma unroll
        for (int mt = 0; mt < 2; ++mt) {
            af[mt][0] = __builtin_bit_cast(bf16x8,
                *(const uint4*)(cb + arow + mt * 2048 + sl0));
            af[mt][1] = __builtin_bit_cast(bf16x8,
                *(const uint4*)(cb + arow + mt * 2048 + sl1));
        }
        if (kt + 1 < NT) stageA(nb, (kt + 1) << 6);
        __builtin_amdgcn_s_setprio(1);
#pragma unroll
        for (int mt = 0; mt < 2; ++mt)
#pragma unroll
            for (int nt = 0; nt < NTW; ++nt)
#pragma unroll
                for (int kk = 0; kk < 2; ++kk)
                    acc[mt][nt] = __builtin_amdgcn_mfma_f32_16x16x32_bf16(
                        af[mt][kk], bfr[nt][kk], acc[mt][nt], 0, 0, 0);
        __builtin_amdgcn_s_setprio(0);
        ph_barrier();                       // BARRIER_A

        // ---- phase 2: read A mt23, stage (kt+2):B -> cb, MFMA mt23 -------
        bf16x8 ag[2][2];
#pragma unroll
        for (int mt = 0; mt < 2; ++mt) {
            ag[mt][0] = __builtin_bit_cast(bf16x8,
                *(const uint4*)(cb + arow + (2 + mt) * 2048 + sl0));
            ag[mt][1] = __builtin_bit_cast(bf16x8,
                *(const uint4*)(cb + arow + (2 + mt) * 2048 + sl1));
        }
        if (kt + 2 < NT) stageB(cb, (kt + 2) << 6);
        __builtin_amdgcn_s_setprio(1);
#pragma unroll
        for (int mt = 0; mt < 2; ++mt)
#pragma unroll
            for (int nt = 0; nt < NTW; ++nt)
#pragma unroll
                for (int kk = 0; kk < 2; ++kk)
                    acc[mt + 2][nt] = __builtin_amdgcn_mfma_f32_16x16x32_bf16(
                        ag[mt][kk], bfr[nt][kk], acc[mt + 2][nt], 0, 0, 0);
        __builtin_amdgcn_s_setprio(0);
        if (kt < NT - 2) {
            if (BI == 3) asm volatile("s_waitcnt vmcnt(3)" ::: "memory");
            else         asm volatile("s_waitcnt vmcnt(2)" ::: "memory");
        } else {
            asm volatile("s_waitcnt vmcnt(0)" ::: "memory");
        }
        ph_barrier();                       // BARRIER_B
    }

    // epilogue: C/D layout row=l4*4+reg, col=l15
#pragma unroll
    for (int nt = 0; nt < NTW; ++nt) {
        const int colg = n0 + wc * WCOLS + nt * 16 + l15;
        const float bv = bias[colg];
#pragma unroll
        for (int mt = 0; mt < 4; ++mt) {
            const int rowb = m0 + wr * 64 + mt * 16 + l4 * 4;
#pragma unroll
            for (int r = 0; r < 4; ++r) {
                const float v = acc[mt][nt][r] + bv;
                if (OUT_BF16)
                    ((u16*)Cout)[(size_t)(rowb + r) * N + colg] = f2bf(v);
                else
                    ((float*)Cout)[(size_t)(rowb + r) * N + colg] = v;
            }
        }
    }
}

// ---------------------------------------------------------------------------
// RoPE cos/sin table: ct/st[t][d2], d2 in [0,64).
// ---------------------------------------------------------------------------
__global__ __launch_bounds__(256) void rope_table(
    float* __restrict__ ct, float* __restrict__ st)
{
    const int i = blockIdx.x * 256 + threadIdx.x;   // t*64 + d2
    const int d2 = i & 63, t = i >> 6;
    const float invf = expf(-(float)d2 * (9.210340371976184f / 64.0f));
    const float fr = (float)t * invf;
    ct[i] = cosf(fr);
    st[i] = sinf(fr);
}

// ---------------------------------------------------------------------------
// Fused RoPE + QKV relayout v3 (round-5 proven).
// ---------------------------------------------------------------------------
__global__ __launch_bounds__(256) void rope_kv(
    const u16* __restrict__ qkv, const float* __restrict__ ct,
    const float* __restrict__ st,
    u16* __restrict__ Qc, u16* __restrict__ Kc, u16* __restrict__ Vt)
{
    __shared__ u16 vtile[128][264];      // 264 = 256 + 8 pad (16B-aligned rows)
    const int tid = threadIdx.x;
    const int blk = blockIdx.x;          // b(4) x h(16) x ttile(4)
    const int tt = blk & 3;
    const int h  = (blk >> 2) & 15;
    const int b  = blk >> 6;
    const int bh = b * 16 + h;

    // ---------------- Q/K: coalesced reads + shfl rope --------------------
    const int c8 = tid & 15;             // 16B chunk within the 128-d head
    const int rg = tid >> 4;             // row within sweep (16 rows/sweep)
    const float sgn = (c8 < 8) ? -1.f : 1.f;

#pragma unroll 4
    for (int s = 0; s < 16; ++s) {
        const int row = s * 16 + rg;     // 0..255
        const int t   = tt * 256 + row;
        const size_t rsrc = (size_t)(b * T_SEQ + t) * QKV_N + h * D_HEAD;
        const size_t rdst = (size_t)(bh * T_SEQ + t) * D_HEAD + c8 * 8;

        // cos/sin for this thread's 8 cols (d2 = (c8&7)*8 + i)
        const float* crow = ct + t * 64 + (c8 & 7) * 8;
        const float* srow = st + t * 64 + (c8 & 7) * 8;
        float cs[8], sn[8];
        *(float4*)(cs)     = *(const float4*)(crow);
        *(float4*)(cs + 4) = *(const float4*)(crow + 4);
        *(float4*)(sn)     = *(const float4*)(srow);
        *(float4*)(sn + 4) = *(const float4*)(srow + 4);

#pragma unroll
        for (int part = 0; part < 2; ++part) {
            uint4 u = *(const uint4*)(qkv + rsrc + part * C_DIM + c8 * 8);
            uint4 pu;
            pu.x = (u32)__shfl_xor((int)u.x, 8, 64);
            pu.y = (u32)__shfl_xor((int)u.y, 8, 64);
            pu.z = (u32)__shfl_xor((int)u.z, 8, 64);
            pu.w = (u32)__shfl_xor((int)u.w, 8, 64);
            float f[8], pf[8], o[8];
            unpack8(u, f); unpack8(pu, pf);
#pragma unroll
            for (int i = 0; i < 8; ++i)
                o[i] = f[i] * cs[i] + sgn * pf[i] * sn[i];
            u16* outp = (part ? Kc : Qc) + rdst;
            *(uint4*)outp = pack8(o);
        }
    }

    // ---------------- V: column stage + coalesced out ---------------------
    const int t = tt * 256 + tid;
    const size_t vsrc = (size_t)(b * T_SEQ + t) * QKV_N + 2 * C_DIM + h * D_HEAD;
#pragma unroll
    for (int c = 0; c < 16; ++c) {
        uint4 v = *(const uint4*)(qkv + vsrc + c * 8);
        u16 e[8];
        e[0] = (u16)(v.x & 0xffff); e[1] = (u16)(v.x >> 16);
        e[2] = (u16)(v.y & 0xffff); e[3] = (u16)(v.y >> 16);
        e[4] = (u16)(v.z & 0xffff); e[5] = (u16)(v.z >> 16);
        e[6] = (u16)(v.w & 0xffff); e[7] = (u16)(v.w >> 16);
#pragma unroll
        for (int j = 0; j < 8; ++j)
            vtile[c * 8 + j][tid] = e[j];
    }
    __syncthreads();

    // coalesced store: 32 lanes cover one row's 256 u16 (512B contiguous)
    const int dl = tid >> 5;             // 0..7: row within pass
    const int jc = (tid & 31) * 8;       // u16 col
    u16* vt = Vt + ((size_t)bh * D_HEAD) * T_SEQ + (size_t)tt * 256;
#pragma unroll
    for (int pass = 0; pass < 16; ++pass) {
        const int d = pass * 8 + dl;
        *(uint4*)(vt + (size_t)d * T_SEQ + jc) = *(const uint4*)&vtile[d][jc];
    }
}

// ---------------------------------------------------------------------------
// MFMA flash attention, 64-row q-tiles (unchanged this round).
// ---------------------------------------------------------------------------
__global__ __launch_bounds__(256) void attn_mfma(
    const u16* __restrict__ Qc,    // [B*H, T, D] roped
    const u16* __restrict__ Kc,    // [B*H, T, D] roped
    const u16* __restrict__ Vt,    // [B*H, D, T]
    u16* __restrict__ y)           // [B, T, C]
{
    __shared__ alignas(16) char KsL[2][16384];   // [cd(16)][row(64)][16B]
    __shared__ alignas(16) char VtsL[2][16384];  // [jc(8)][drow(128)][16B]
    __shared__ alignas(16) char PwL[4][2176];    // per-wave [jc(8)][q(16)][16B]+pad

    const int tid  = threadIdx.x;
    const int lane = tid & 63;
    const int w    = tid >> 6;
    const int l15  = lane & 15;
    const int l4   = lane >> 4;
    const int p    = blockIdx.x;     // 0..7
    const int bh   = blockIdx.y;     // 0..63
    const int h    = bh & 15;
    const int b    = bh >> 4;

    const size_t kbase = (size_t)bh * T_SEQ * D_HEAD;
    const size_t vbase = (size_t)bh * D_HEAD * T_SEQ;
    const float scale = 0.08838834764831845f;   // 1/sqrt(128)
    char* pw = PwL[w];

    for (int half = 0; half < 2; ++half) {
        const int qt = half ? (15 - p) : p;

        // Q fragments (A-layout: m=lane&15, k=(lane>>4)*8+j)
        const int qrow = qt * 64 + w * 16 + l15;
        const u16* qptr = Qc + ((size_t)(bh * T_SEQ + qrow)) * D_HEAD;
        bf16x8 qf[4];
#pragma unroll
        for (int f = 0; f < 4; ++f)
            qf[f] = __builtin_bit_cast(bf16x8, *(const uint4*)(qptr + f * 32 + l4 * 8));

        f32x4 o[8] = {};                 // O[q=l4*4+r][d=db*16+l15]
        float lrow[4] = {};              // per-lane partial denominators

        __syncthreads();   // prior half's readers done before restaging buf 0

        // prologue: stage kt = 0 into buffer 0
        {
            const u16* ksrc = Kc + kbase + (size_t)(0 * 64 + lane) * D_HEAD;
#pragma unroll
            for (int i = 0; i < 4; ++i) {
                const int cd = w * 4 + i;
                __builtin_amdgcn_global_load_lds(AS1C(ksrc + cd * 8),
                                                 AS3(KsL[0] + cd * 1024), 16, 0, 0);
            }
#pragma unroll
            for (int i = 0; i < 4; ++i) {
                const int jc = w + (i >> 1) * 4;
                const int dh = i & 1;
                const u16* vsrc = Vt + vbase + (size_t)(dh * 64 + lane) * T_SEQ
                                  + 0 * 64 + jc * 8;
                __builtin_amdgcn_global_load_lds(AS1C(vsrc),
                                                 AS3(VtsL[0] + jc * 2048 + dh * 1024), 16, 0, 0);
            }
        }

        int buf = 0;
        for (int kt = 0; kt <= qt; ++kt, buf ^= 1) {
            __syncthreads();     // buf visible; buf^1's readers (kt-2) done
            if (kt < qt) {
                const int kn = kt + 1;
                char* kb = KsL[buf ^ 1];
                char* vb = VtsL[buf ^ 1];
                const u16* ksrc = Kc + kbase + (size_t)(kn * 64 + lane) * D_HEAD;
#pragma unroll
                for (int i = 0; i < 4; ++i) {
                    const int cd = w * 4 + i;
                    __builtin_amdgcn_global_load_lds(AS1C(ksrc + cd * 8),
                                                     AS3(kb + cd * 1024), 16, 0, 0);
                }
#pragma unroll
                for (int i = 0; i < 4; ++i) {
                    const int jc = w + (i >> 1) * 4;
                    const int dh = i & 1;
                    const u16* vsrc = Vt + vbase + (size_t)(dh * 64 + lane) * T_SEQ
                                      + kn * 64 + jc * 8;
                    __builtin_amdgcn_global_load_lds(AS1C(vsrc),
                                                     AS3(vb + jc * 2048 + dh * 1024), 16, 0, 0);
                }
            }

            const char* kbuf = KsL[buf];
            const char* vbuf = VtsL[buf];

            // QK^T: 16 MFMAs
            f32x4 sacc[4] = {};
#pragma unroll
            for (int nb = 0; nb < 4; ++nb)
#pragma unroll
                for (int kc = 0; kc < 4; ++kc) {
                    bf16x8 kf = __builtin_bit_cast(bf16x8,
                        *(const uint4*)(kbuf + (kc * 4 + l4) * 1024 + (nb * 16 + l15) * 16));
                    sacc[nb] = __builtin_amdgcn_mfma_f32_16x16x32_bf16(
                        qf[kc], kf, sacc[nb], 0, 0, 0);
                }

            // P = exp(s*scale - 8), causal-masked on diagonal; partial denoms
#pragma unroll
            for (int nb = 0; nb < 4; ++nb)
#pragma unroll
                for (int r = 0; r < 4; ++r) {
                    const bool masked =
                        (kt == qt) && ((nb * 16 + l15) > (w * 16 + l4 * 4 + r));
                    const float e = masked ? 0.f
                        : __expf(sacc[nb][r] * scale - 8.0f);
                    sacc[nb][r] = e;
                    lrow[r] += e;
                }

            // P: C-layout regs -> bf16 -> per-wave LDS in A-layout chunks
#pragma unroll
            for (int nb = 0; nb < 4; ++nb)
#pragma unroll
                for (int r = 0; r < 4; ++r) {
                    const int j = nb * 16 + l15;
                    const int q = l4 * 4 + r;
                    *(u16*)(pw + (j >> 3) * 272 + q * 16 + (j & 7) * 2) =
                        f2bf(sacc[nb][r]);
                }

            // PV: O += P @ V
            bf16x8 pf[2];
#pragma unroll
            for (int kc2 = 0; kc2 < 2; ++kc2)
                pf[kc2] = __builtin_bit_cast(bf16x8,
                    *(const uint4*)(pw + (kc2 * 4 + l4) * 272 + l15 * 16));
#pragma unroll
            for (int db = 0; db < 8; ++db)
#pragma unroll
                for (int kc2 = 0; kc2 < 2; ++kc2) {
                    bf16x8 vf = __builtin_bit_cast(bf16x8,
                        *(const uint4*)(vbuf + (kc2 * 4 + l4) * 2048 + (db * 16 + l15) * 16));
                    o[db] = __builtin_amdgcn_mfma_f32_16x16x32_bf16(
                        pf[kc2], vf, o[db], 0, 0, 0);
                }
        }

        // end-of-row reduce of denominators across the 16 l15 lanes
        float inv[4];
#pragma unroll
        for (int r = 0; r < 4; ++r) {
            float ls = lrow[r];
#pragma unroll
            for (int off = 1; off < 16; off <<= 1)
                ls += __shfl_xor(ls, off, 64);
            inv[r] = 1.f / ls;
        }
#pragma unroll
        for (int db = 0; db < 8; ++db)
#pragma unroll
            for (int r = 0; r < 4; ++r) {
                const int q = qt * 64 + w * 16 + l4 * 4 + r;
                const int d = h * D_HEAD + db * 16 + l15;
                y[(size_t)(b * T_SEQ + q) * C_DIM + d] = f2bf(o[db][r] * inv[r]);
            }
    }
}

// ---------------------------------------------------------------------------
extern "C" void kernel_launch(void* const* d_in, const int* in_sizes, int n_in,
                              void* d_out, int out_size, void* d_ws, size_t ws_size,
                              hipStream_t stream) {
    const float* x      = (const float*)d_in[0];
    const float* w_attn = (const float*)d_in[1];
    const float* b_attn = (const float*)d_in[2];
    const float* w_proj = (const float*)d_in[3];
    const float* b_proj = (const float*)d_in[4];
    float* out = (float*)d_out;

    char* ws = (char*)d_ws;
    u16* xb   = (u16*)(ws);                        // [4096][2048]    16.78 MB
    u16* waT  = (u16*)(ws + 16777216);             // [6144][2048]    25.17 MB
    u16* Qc   = (u16*)(ws);                        // [64][1024][128] 16.78 MB
    u16* Kc   = (u16*)(ws + 16777216);             // [64][1024][128] 16.78 MB
    u16* Vt   = (u16*)(ws + 33554432);             // [64][128][1024] 16.78 MB
    u16* qkvb = (u16*)(ws + 50331648);             // [4096][6144]    50.33 MB
    u16* wpT  = (u16*)(ws + 50331648);             // [2048][2048]     8.39 MB (after rope_kv)
    u16* yb   = (u16*)(ws + 100663296);            // [4096][2048]    16.78 MB
    float* ct = (float*)(ws + 100663296);          // [1024][64] 256 KB (dead before attn)
    float* st = ct + 65536;

    cast_bf16<<<(BT * C_DIM / 4) / 256, 256, 0, stream>>>(x, xb);
    transpose_cast<<<dim3(QKV_N / 32, C_DIM / 32), 256, 0, stream>>>(w_attn, waT, C_DIM, QKV_N);
    rope_table<<<(T_SEQ * 64) / 256, 256, 0, stream>>>(ct, st);

    gemm_bf16_q32<1><<<dim3(QKV_N / 128, BT / 128), 512, 0, stream>>>(
        xb, waT, b_attn, qkvb, BT, QKV_N, C_DIM);

    rope_kv<<<256, 256, 0, stream>>>(qkvb, ct, st, Qc, Kc, Vt);

    transpose_cast<<<dim3(C_DIM / 32, C_DIM / 32), 256, 0, stream>>>(w_proj, wpT, C_DIM, C_DIM);

    attn_mfma<<<dim3(8, 4 * H_NUM), 256, 0, stream>>>(Qc, Kc, Vt, yb);

    gemm_bf16_ov<128, 0><<<dim3(C_DIM / 128, BT / 128), 512, 0, stream>>>(
        yb, wpT, b_proj, out, BT, C_DIM, C_DIM);
}

// Round 8
// 352.711 us; speedup vs baseline: 1.0649x; 1.0649x over previous
//
#include <hip/hip_runtime.h>
#include <math.h>

#define T_SEQ 1024
#define C_DIM 2048
#define H_NUM 16
#define D_HEAD 128
#define BT 4096              // B*T rows
#define QKV_N 6144           // 3*C

typedef __bf16 bf16x8 __attribute__((ext_vector_type(8)));
typedef float f32x4 __attribute__((ext_vector_type(4)));
typedef unsigned short u16;
typedef unsigned int u32;

#define AS1C(p) ((const __attribute__((address_space(1))) void*)(p))
#define AS3(p)  ((__attribute__((address_space(3))) void*)(p))

__device__ __forceinline__ u16 f2bf(float f) {
    u32 u = __builtin_bit_cast(u32, f);
    u += 0x7fffu + ((u >> 16) & 1u);          // RNE
    return (u16)(u >> 16);
}
__device__ __forceinline__ void unpack8(uint4 u, float* f) {
    const u32 w0 = u.x, w1 = u.y, w2 = u.z, w3 = u.w;
    f[0] = __builtin_bit_cast(float, w0 << 16);
    f[1] = __builtin_bit_cast(float, w0 & 0xffff0000u);
    f[2] = __builtin_bit_cast(float, w1 << 16);
    f[3] = __builtin_bit_cast(float, w1 & 0xffff0000u);
    f[4] = __builtin_bit_cast(float, w2 << 16);
    f[5] = __builtin_bit_cast(float, w2 & 0xffff0000u);
    f[6] = __builtin_bit_cast(float, w3 << 16);
    f[7] = __builtin_bit_cast(float, w3 & 0xffff0000u);
}
__device__ __forceinline__ uint4 pack8(const float* f) {
    uint4 u;
    u.x = (u32)f2bf(f[0]) | ((u32)f2bf(f[1]) << 16);
    u.y = (u32)f2bf(f[2]) | ((u32)f2bf(f[3]) << 16);
    u.z = (u32)f2bf(f[4]) | ((u32)f2bf(f[5]) << 16);
    u.w = (u32)f2bf(f[6]) | ((u32)f2bf(f[7]) << 16);
    return u;
}

__device__ __forceinline__ void ph_barrier() {
    asm volatile("" ::: "memory");
    __builtin_amdgcn_s_barrier();
    asm volatile("" ::: "memory");
}

// ---------------------------------------------------------------------------
// Elementwise fp32 -> bf16 cast (x -> xb).
// ---------------------------------------------------------------------------
__global__ __launch_bounds__(256) void cast_bf16(
    const float* __restrict__ in, u16* __restrict__ out)
{
    int i = blockIdx.x * 256 + threadIdx.x;
    float4 v = ((const float4*)in)[i];
    ushort4 o;
    o.x = f2bf(v.x); o.y = f2bf(v.y); o.z = f2bf(v.z); o.w = f2bf(v.w);
    ((ushort4*)out)[i] = o;
}

// ---------------------------------------------------------------------------
// fp32 [R][Cc] -> bf16 [Cc][R] transpose+cast. 32x32 tile, 256 threads.
// ---------------------------------------------------------------------------
__global__ __launch_bounds__(256) void transpose_cast(
    const float* __restrict__ in, u16* __restrict__ out, int R, int Cc)
{
    __shared__ float tile[32][33];
    const int c0 = blockIdx.x * 32, r0 = blockIdx.y * 32;
    const int tx = threadIdx.x & 31, ty = threadIdx.x >> 5;  // ty 0..7
#pragma unroll
    for (int i = 0; i < 32; i += 8)
        tile[ty + i][tx] = in[(size_t)(r0 + ty + i) * Cc + c0 + tx];
    __syncthreads();
#pragma unroll
    for (int i = 0; i < 32; i += 8)
        out[(size_t)(c0 + ty + i) * R + r0 + tx] = f2bf(tile[tx][ty + i]);
}

// ---------------------------------------------------------------------------
// 128xBN-tile 8-wave MFMA GEMM, 2 blocks/CU (round-6 proven optimum: QKV
// 94 us @ MfmaUtil 50%). The GEMM response surface is now mapped on all
// sides of this point (256-tile 1-blk: 106; 8-phase fenced: 141; 4-phase:
// 127; BK=32 3-blk: 131) — this is the local optimum; keep frozen.
// ---------------------------------------------------------------------------
template <int BN, int OUT_BF16>
__global__ __launch_bounds__(512, 4) void gemm_bf16_ov(
    const u16* __restrict__ A,    // [M][K] bf16
    const u16* __restrict__ Bt,   // [N][K] bf16 (B transposed)
    const float* __restrict__ bias,
    void* __restrict__ Cout,      // bf16 [M][N] or fp32 [M][N]
    int M, int N, int K)
{
    constexpr int BI  = BN / 64;         // B stage issues per wave
    constexpr int NTW = BN / 64;         // n-frags per wave
    constexpr int WCOLS = BN / 4;        // cols per wave
    __shared__ alignas(16) char lds[2][16384 + BN * 128];  // [buf][A 16K | B]

    const int tid  = threadIdx.x;
    const int lane = tid & 63;
    const int w    = tid >> 6;      // 0..7
    const int wr   = w >> 2;        // 0..1 (M)
    const int wc   = w & 3;         // 0..3 (N)
    const int l15  = lane & 15;
    const int l4   = lane >> 4;
    const int m0   = blockIdx.y * 128;
    const int n0   = blockIdx.x * BN;
    const int NT   = K >> 6;        // K-tiles of 64

    f32x4 acc[4][NTW] = {};

    const int srow  = w * 16 + (lane >> 3);          // A rows, +i*8 per issue
    const int sslot = (lane & 7) ^ (lane >> 3);      // row&7 == lane>>3
    const size_t aoff = (size_t)(m0 + srow) * K + sslot * 8;
    const int brow_s = w * 8 + (lane >> 3);          // B rows, +i*64 per issue
    const size_t boff = (size_t)(n0 + brow_s) * K + sslot * 8;

    auto stageA = [&](char* buf, int k0) {           // 128 rows, 2 issues
#pragma unroll
        for (int i = 0; i < 2; ++i)
            __builtin_amdgcn_global_load_lds(
                AS1C(A + aoff + (size_t)(i * 8) * K + k0),
                AS3(buf + w * 2048 + i * 1024), 16, 0, 0);
    };
    auto stageB = [&](char* buf, int k0) {           // BN rows, BI issues
#pragma unroll
        for (int i = 0; i < BI; ++i)
            __builtin_amdgcn_global_load_lds(
                AS1C(Bt + boff + (size_t)(i * 64) * K + k0),
                AS3(buf + 16384 + i * 8192 + w * 1024), 16, 0, 0);
    };

    // prologue: B(kt0), A(kt0) -> buf0; B(kt1) -> buf1.
    stageB(lds[0], 0);
    stageA(lds[0], 0);
    stageB(lds[1], 64);
    if (BI == 3) asm volatile("s_waitcnt vmcnt(3)" ::: "memory");
    else         asm volatile("s_waitcnt vmcnt(2)" ::: "memory");
    ph_barrier();

    const int sl0  = (l4 ^ (l15 & 7)) << 4;
    const int sl1  = sl0 ^ 64;
    const int arow = (wr * 64 + l15) * 128;
    const int brow = 16384 + (wc * WCOLS + l15) * 128;

    for (int kt = 0; kt < NT; ++kt) {
        char* cb = lds[kt & 1];
        char* nb = lds[(kt & 1) ^ 1];

        // ---- phase 1: read B(all)+A mt01, stage (kt+1):A, MFMA mt01 ------
        bf16x8 bfr[NTW][2], af[2][2];
#pragma unroll
        for (int nt = 0; nt < NTW; ++nt) {
            bfr[nt][0] = __builtin_bit_cast(bf16x8,
                *(const uint4*)(cb + brow + nt * 2048 + sl0));
            bfr[nt][1] = __builtin_bit_cast(bf16x8,
                *(const uint4*)(cb + brow + nt * 2048 + sl1));
        }
#pragma unroll
        for (int mt = 0; mt < 2; ++mt) {
            af[mt][0] = __builtin_bit_cast(bf16x8,
                *(const uint4*)(cb + arow + mt * 2048 + sl0));
            af[mt][1] = __builtin_bit_cast(bf16x8,
                *(const uint4*)(cb + arow + mt * 2048 + sl1));
        }
        if (kt + 1 < NT) stageA(nb, (kt + 1) << 6);
        __builtin_amdgcn_s_setprio(1);
#pragma unroll
        for (int mt = 0; mt < 2; ++mt)
#pragma unroll
            for (int nt = 0; nt < NTW; ++nt)
#pragma unroll
                for (int kk = 0; kk < 2; ++kk)
                    acc[mt][nt] = __builtin_amdgcn_mfma_f32_16x16x32_bf16(
                        af[mt][kk], bfr[nt][kk], acc[mt][nt], 0, 0, 0);
        __builtin_amdgcn_s_setprio(0);
        ph_barrier();                       // BARRIER_A

        // ---- phase 2: read A mt23, stage (kt+2):B -> cb, MFMA mt23 -------
        bf16x8 ag[2][2];
#pragma unroll
        for (int mt = 0; mt < 2; ++mt) {
            ag[mt][0] = __builtin_bit_cast(bf16x8,
                *(const uint4*)(cb + arow + (2 + mt) * 2048 + sl0));
            ag[mt][1] = __builtin_bit_cast(bf16x8,
                *(const uint4*)(cb + arow + (2 + mt) * 2048 + sl1));
        }
        if (kt + 2 < NT) stageB(cb, (kt + 2) << 6);
        __builtin_amdgcn_s_setprio(1);
#pragma unroll
        for (int mt = 0; mt < 2; ++mt)
#pragma unroll
            for (int nt = 0; nt < NTW; ++nt)
#pragma unroll
                for (int kk = 0; kk < 2; ++kk)
                    acc[mt + 2][nt] = __builtin_amdgcn_mfma_f32_16x16x32_bf16(
                        ag[mt][kk], bfr[nt][kk], acc[mt + 2][nt], 0, 0, 0);
        __builtin_amdgcn_s_setprio(0);
        if (kt < NT - 2) {
            if (BI == 3) asm volatile("s_waitcnt vmcnt(3)" ::: "memory");
            else         asm volatile("s_waitcnt vmcnt(2)" ::: "memory");
        } else {
            asm volatile("s_waitcnt vmcnt(0)" ::: "memory");
        }
        ph_barrier();                       // BARRIER_B
    }

    // epilogue: C/D layout row=l4*4+reg, col=l15
#pragma unroll
    for (int nt = 0; nt < NTW; ++nt) {
        const int colg = n0 + wc * WCOLS + nt * 16 + l15;
        const float bv = bias[colg];
#pragma unroll
        for (int mt = 0; mt < 4; ++mt) {
            const int rowb = m0 + wr * 64 + mt * 16 + l4 * 4;
#pragma unroll
            for (int r = 0; r < 4; ++r) {
                const float v = acc[mt][nt][r] + bv;
                if (OUT_BF16)
                    ((u16*)Cout)[(size_t)(rowb + r) * N + colg] = f2bf(v);
                else
                    ((float*)Cout)[(size_t)(rowb + r) * N + colg] = v;
            }
        }
    }
}

// ---------------------------------------------------------------------------
// RoPE cos/sin table: ct/st[t][d2], d2 in [0,64).
// ---------------------------------------------------------------------------
__global__ __launch_bounds__(256) void rope_table(
    float* __restrict__ ct, float* __restrict__ st)
{
    const int i = blockIdx.x * 256 + threadIdx.x;   // t*64 + d2
    const int d2 = i & 63, t = i >> 6;
    const float invf = expf(-(float)d2 * (9.210340371976184f / 64.0f));
    const float fr = (float)t * invf;
    ct[i] = cosf(fr);
    st[i] = sinf(fr);
}

// ---------------------------------------------------------------------------
// Fused RoPE + QKV relayout v3 (round-5 proven).
// ---------------------------------------------------------------------------
__global__ __launch_bounds__(256) void rope_kv(
    const u16* __restrict__ qkv, const float* __restrict__ ct,
    const float* __restrict__ st,
    u16* __restrict__ Qc, u16* __restrict__ Kc, u16* __restrict__ Vt)
{
    __shared__ u16 vtile[128][264];      // 264 = 256 + 8 pad (16B-aligned rows)
    const int tid = threadIdx.x;
    const int blk = blockIdx.x;          // b(4) x h(16) x ttile(4)
    const int tt = blk & 3;
    const int h  = (blk >> 2) & 15;
    const int b  = blk >> 6;
    const int bh = b * 16 + h;

    // ---------------- Q/K: coalesced reads + shfl rope --------------------
    const int c8 = tid & 15;             // 16B chunk within the 128-d head
    const int rg = tid >> 4;             // row within sweep (16 rows/sweep)
    const float sgn = (c8 < 8) ? -1.f : 1.f;

#pragma unroll 4
    for (int s = 0; s < 16; ++s) {
        const int row = s * 16 + rg;     // 0..255
        const int t   = tt * 256 + row;
        const size_t rsrc = (size_t)(b * T_SEQ + t) * QKV_N + h * D_HEAD;
        const size_t rdst = (size_t)(bh * T_SEQ + t) * D_HEAD + c8 * 8;

        // cos/sin for this thread's 8 cols (d2 = (c8&7)*8 + i)
        const float* crow = ct + t * 64 + (c8 & 7) * 8;
        const float* srow = st + t * 64 + (c8 & 7) * 8;
        float cs[8], sn[8];
        *(float4*)(cs)     = *(const float4*)(crow);
        *(float4*)(cs + 4) = *(const float4*)(crow + 4);
        *(float4*)(sn)     = *(const float4*)(srow);
        *(float4*)(sn + 4) = *(const float4*)(srow + 4);

#pragma unroll
        for (int part = 0; part < 2; ++part) {
            uint4 u = *(const uint4*)(qkv + rsrc + part * C_DIM + c8 * 8);
            uint4 pu;
            pu.x = (u32)__shfl_xor((int)u.x, 8, 64);
            pu.y = (u32)__shfl_xor((int)u.y, 8, 64);
            pu.z = (u32)__shfl_xor((int)u.z, 8, 64);
            pu.w = (u32)__shfl_xor((int)u.w, 8, 64);
            float f[8], pf[8], o[8];
            unpack8(u, f); unpack8(pu, pf);
#pragma unroll
            for (int i = 0; i < 8; ++i)
                o[i] = f[i] * cs[i] + sgn * pf[i] * sn[i];
            u16* outp = (part ? Kc : Qc) + rdst;
            *(uint4*)outp = pack8(o);
        }
    }

    // ---------------- V: column stage + coalesced out ---------------------
    const int t = tt * 256 + tid;
    const size_t vsrc = (size_t)(b * T_SEQ + t) * QKV_N + 2 * C_DIM + h * D_HEAD;
#pragma unroll
    for (int c = 0; c < 16; ++c) {
        uint4 v = *(const uint4*)(qkv + vsrc + c * 8);
        u16 e[8];
        e[0] = (u16)(v.x & 0xffff); e[1] = (u16)(v.x >> 16);
        e[2] = (u16)(v.y & 0xffff); e[3] = (u16)(v.y >> 16);
        e[4] = (u16)(v.z & 0xffff); e[5] = (u16)(v.z >> 16);
        e[6] = (u16)(v.w & 0xffff); e[7] = (u16)(v.w >> 16);
#pragma unroll
        for (int j = 0; j < 8; ++j)
            vtile[c * 8 + j][tid] = e[j];
    }
    __syncthreads();

    // coalesced store: 32 lanes cover one row's 256 u16 (512B contiguous)
    const int dl = tid >> 5;             // 0..7: row within pass
    const int jc = (tid & 31) * 8;       // u16 col
    u16* vt = Vt + ((size_t)bh * D_HEAD) * T_SEQ + (size_t)tt * 256;
#pragma unroll
    for (int pass = 0; pass < 16; ++pass) {
        const int d = pass * 8 + dl;
        *(uint4*)(vt + (size_t)d * T_SEQ + jc) = *(const uint4*)&vtile[d][jc];
    }
}

// ---------------------------------------------------------------------------
// MFMA flash attention, 64-row q-tiles. Round-8 change: s_setprio(1/0)
// around the QK^T and PV MFMA clusters (T5). Mechanism match: 2 independent
// blocks/CU at different loop phases — setprio favors the MFMA-feeding wave
// over other blocks' staging/softmax VALU (m191 regime: +4-7%; null only in
// barrier-locked single-block GEMM).  Bank-conflict check done before any
// swizzle: K/V frag reads are stride-16B within 8-lane groups -> each
// 8-lane service group covers all 32 banks -> conflict-free as-is.
// ---------------------------------------------------------------------------
__global__ __launch_bounds__(256) void attn_mfma(
    const u16* __restrict__ Qc,    // [B*H, T, D] roped
    const u16* __restrict__ Kc,    // [B*H, T, D] roped
    const u16* __restrict__ Vt,    // [B*H, D, T]
    u16* __restrict__ y)           // [B, T, C]
{
    __shared__ alignas(16) char KsL[2][16384];   // [cd(16)][row(64)][16B]
    __shared__ alignas(16) char VtsL[2][16384];  // [jc(8)][drow(128)][16B]
    __shared__ alignas(16) char PwL[4][2176];    // per-wave [jc(8)][q(16)][16B]+pad

    const int tid  = threadIdx.x;
    const int lane = tid & 63;
    const int w    = tid >> 6;
    const int l15  = lane & 15;
    const int l4   = lane >> 4;
    const int p    = blockIdx.x;     // 0..7
    const int bh   = blockIdx.y;     // 0..63
    const int h    = bh & 15;
    const int b    = bh >> 4;

    const size_t kbase = (size_t)bh * T_SEQ * D_HEAD;
    const size_t vbase = (size_t)bh * D_HEAD * T_SEQ;
    const float scale = 0.08838834764831845f;   // 1/sqrt(128)
    char* pw = PwL[w];

    for (int half = 0; half < 2; ++half) {
        const int qt = half ? (15 - p) : p;

        // Q fragments (A-layout: m=lane&15, k=(lane>>4)*8+j)
        const int qrow = qt * 64 + w * 16 + l15;
        const u16* qptr = Qc + ((size_t)(bh * T_SEQ + qrow)) * D_HEAD;
        bf16x8 qf[4];
#pragma unroll
        for (int f = 0; f < 4; ++f)
            qf[f] = __builtin_bit_cast(bf16x8, *(const uint4*)(qptr + f * 32 + l4 * 8));

        f32x4 o[8] = {};                 // O[q=l4*4+r][d=db*16+l15]
        float lrow[4] = {};              // per-lane partial denominators

        __syncthreads();   // prior half's readers done before restaging buf 0

        // prologue: stage kt = 0 into buffer 0
        {
            const u16* ksrc = Kc + kbase + (size_t)(0 * 64 + lane) * D_HEAD;
#pragma unroll
            for (int i = 0; i < 4; ++i) {
                const int cd = w * 4 + i;
                __builtin_amdgcn_global_load_lds(AS1C(ksrc + cd * 8),
                                                 AS3(KsL[0] + cd * 1024), 16, 0, 0);
            }
#pragma unroll
            for (int i = 0; i < 4; ++i) {
                const int jc = w + (i >> 1) * 4;
                const int dh = i & 1;
                const u16* vsrc = Vt + vbase + (size_t)(dh * 64 + lane) * T_SEQ
                                  + 0 * 64 + jc * 8;
                __builtin_amdgcn_global_load_lds(AS1C(vsrc),
                                                 AS3(VtsL[0] + jc * 2048 + dh * 1024), 16, 0, 0);
            }
        }

        int buf = 0;
        for (int kt = 0; kt <= qt; ++kt, buf ^= 1) {
            __syncthreads();     // buf visible; buf^1's readers (kt-2) done
            if (kt < qt) {
                const int kn = kt + 1;
                char* kb = KsL[buf ^ 1];
                char* vb = VtsL[buf ^ 1];
                const u16* ksrc = Kc + kbase + (size_t)(kn * 64 + lane) * D_HEAD;
#pragma unroll
                for (int i = 0; i < 4; ++i) {
                    const int cd = w * 4 + i;
                    __builtin_amdgcn_global_load_lds(AS1C(ksrc + cd * 8),
                                                     AS3(kb + cd * 1024), 16, 0, 0);
                }
#pragma unroll
                for (int i = 0; i < 4; ++i) {
                    const int jc = w + (i >> 1) * 4;
                    const int dh = i & 1;
                    const u16* vsrc = Vt + vbase + (size_t)(dh * 64 + lane) * T_SEQ
                                      + kn * 64 + jc * 8;
                    __builtin_amdgcn_global_load_lds(AS1C(vsrc),
                                                     AS3(vb + jc * 2048 + dh * 1024), 16, 0, 0);
                }
            }

            const char* kbuf = KsL[buf];
            const char* vbuf = VtsL[buf];

            // QK^T: 16 MFMAs (setprio-wrapped)
            f32x4 sacc[4] = {};
            __builtin_amdgcn_s_setprio(1);
#pragma unroll
            for (int nb = 0; nb < 4; ++nb)
#pragma unroll
                for (int kc = 0; kc < 4; ++kc) {
                    bf16x8 kf = __builtin_bit_cast(bf16x8,
                        *(const uint4*)(kbuf + (kc * 4 + l4) * 1024 + (nb * 16 + l15) * 16));
                    sacc[nb] = __builtin_amdgcn_mfma_f32_16x16x32_bf16(
                        qf[kc], kf, sacc[nb], 0, 0, 0);
                }
            __builtin_amdgcn_s_setprio(0);

            // P = exp(s*scale - 8), causal-masked on diagonal; partial denoms
#pragma unroll
            for (int nb = 0; nb < 4; ++nb)
#pragma unroll
                for (int r = 0; r < 4; ++r) {
                    const bool masked =
                        (kt == qt) && ((nb * 16 + l15) > (w * 16 + l4 * 4 + r));
                    const float e = masked ? 0.f
                        : __expf(sacc[nb][r] * scale - 8.0f);
                    sacc[nb][r] = e;
                    lrow[r] += e;
                }

            // P: C-layout regs -> bf16 -> per-wave LDS in A-layout chunks
#pragma unroll
            for (int nb = 0; nb < 4; ++nb)
#pragma unroll
                for (int r = 0; r < 4; ++r) {
                    const int j = nb * 16 + l15;
                    const int q = l4 * 4 + r;
                    *(u16*)(pw + (j >> 3) * 272 + q * 16 + (j & 7) * 2) =
                        f2bf(sacc[nb][r]);
                }

            // PV: O += P @ V (setprio-wrapped)
            bf16x8 pf[2];
#pragma unroll
            for (int kc2 = 0; kc2 < 2; ++kc2)
                pf[kc2] = __builtin_bit_cast(bf16x8,
                    *(const uint4*)(pw + (kc2 * 4 + l4) * 272 + l15 * 16));
            __builtin_amdgcn_s_setprio(1);
#pragma unroll
            for (int db = 0; db < 8; ++db)
#pragma unroll
                for (int kc2 = 0; kc2 < 2; ++kc2) {
                    bf16x8 vf = __builtin_bit_cast(bf16x8,
                        *(const uint4*)(vbuf + (kc2 * 4 + l4) * 2048 + (db * 16 + l15) * 16));
                    o[db] = __builtin_amdgcn_mfma_f32_16x16x32_bf16(
                        pf[kc2], vf, o[db], 0, 0, 0);
                }
            __builtin_amdgcn_s_setprio(0);
        }

        // end-of-row reduce of denominators across the 16 l15 lanes
        float inv[4];
#pragma unroll
        for (int r = 0; r < 4; ++r) {
            float ls = lrow[r];
#pragma unroll
            for (int off = 1; off < 16; off <<= 1)
                ls += __shfl_xor(ls, off, 64);
            inv[r] = 1.f / ls;
        }
#pragma unroll
        for (int db = 0; db < 8; ++db)
#pragma unroll
            for (int r = 0; r < 4; ++r) {
                const int q = qt * 64 + w * 16 + l4 * 4 + r;
                const int d = h * D_HEAD + db * 16 + l15;
                y[(size_t)(b * T_SEQ + q) * C_DIM + d] = f2bf(o[db][r] * inv[r]);
            }
    }
}

// ---------------------------------------------------------------------------
extern "C" void kernel_launch(void* const* d_in, const int* in_sizes, int n_in,
                              void* d_out, int out_size, void* d_ws, size_t ws_size,
                              hipStream_t stream) {
    const float* x      = (const float*)d_in[0];
    const float* w_attn = (const float*)d_in[1];
    const float* b_attn = (const float*)d_in[2];
    const float* w_proj = (const float*)d_in[3];
    const float* b_proj = (const float*)d_in[4];
    float* out = (float*)d_out;

    char* ws = (char*)d_ws;
    u16* xb   = (u16*)(ws);                        // [4096][2048]    16.78 MB
    u16* waT  = (u16*)(ws + 16777216);             // [6144][2048]    25.17 MB
    u16* Qc   = (u16*)(ws);                        // [64][1024][128] 16.78 MB
    u16* Kc   = (u16*)(ws + 16777216);             // [64][1024][128] 16.78 MB
    u16* Vt   = (u16*)(ws + 33554432);             // [64][128][1024] 16.78 MB
    u16* qkvb = (u16*)(ws + 50331648);             // [4096][6144]    50.33 MB
    u16* wpT  = (u16*)(ws + 50331648);             // [2048][2048]     8.39 MB (after rope_kv)
    u16* yb   = (u16*)(ws + 100663296);            // [4096][2048]    16.78 MB
    float* ct = (float*)(ws + 100663296);          // [1024][64] 256 KB (dead before attn)
    float* st = ct + 65536;

    cast_bf16<<<(BT * C_DIM / 4) / 256, 256, 0, stream>>>(x, xb);
    transpose_cast<<<dim3(QKV_N / 32, C_DIM / 32), 256, 0, stream>>>(w_attn, waT, C_DIM, QKV_N);
    rope_table<<<(T_SEQ * 64) / 256, 256, 0, stream>>>(ct, st);

    gemm_bf16_ov<192, 1><<<dim3(QKV_N / 192, BT / 128), 512, 0, stream>>>(
        xb, waT, b_attn, qkvb, BT, QKV_N, C_DIM);

    rope_kv<<<256, 256, 0, stream>>>(qkvb, ct, st, Qc, Kc, Vt);

    transpose_cast<<<dim3(C_DIM / 32, C_DIM / 32), 256, 0, stream>>>(w_proj, wpT, C_DIM, C_DIM);

    attn_mfma<<<dim3(8, 4 * H_NUM), 256, 0, stream>>>(Qc, Kc, Vt, yb);

    gemm_bf16_ov<128, 0><<<dim3(C_DIM / 128, BT / 128), 512, 0, stream>>>(
        yb, wpT, b_proj, out, BT, C_DIM, C_DIM);
}

// Round 9
// 337.246 us; speedup vs baseline: 1.1138x; 1.0459x over previous
//
#include <hip/hip_runtime.h>
#include <math.h>

#define T_SEQ 1024
#define C_DIM 2048
#define H_NUM 16
#define D_HEAD 128
#define BT 4096              // B*T rows
#define QKV_N 6144           // 3*C

typedef __bf16 bf16x8 __attribute__((ext_vector_type(8)));
typedef float f32x4 __attribute__((ext_vector_type(4)));
typedef unsigned short u16;
typedef unsigned int u32;

#define AS1C(p) ((const __attribute__((address_space(1))) void*)(p))
#define AS3(p)  ((__attribute__((address_space(3))) void*)(p))

__device__ __forceinline__ u16 f2bf(float f) {
    u32 u = __builtin_bit_cast(u32, f);
    u += 0x7fffu + ((u >> 16) & 1u);          // RNE
    return (u16)(u >> 16);
}
__device__ __forceinline__ void unpack8(uint4 u, float* f) {
    const u32 w0 = u.x, w1 = u.y, w2 = u.z, w3 = u.w;
    f[0] = __builtin_bit_cast(float, w0 << 16);
    f[1] = __builtin_bit_cast(float, w0 & 0xffff0000u);
    f[2] = __builtin_bit_cast(float, w1 << 16);
    f[3] = __builtin_bit_cast(float, w1 & 0xffff0000u);
    f[4] = __builtin_bit_cast(float, w2 << 16);
    f[5] = __builtin_bit_cast(float, w2 & 0xffff0000u);
    f[6] = __builtin_bit_cast(float, w3 << 16);
    f[7] = __builtin_bit_cast(float, w3 & 0xffff0000u);
}
__device__ __forceinline__ uint4 pack8(const float* f) {
    uint4 u;
    u.x = (u32)f2bf(f[0]) | ((u32)f2bf(f[1]) << 16);
    u.y = (u32)f2bf(f[2]) | ((u32)f2bf(f[3]) << 16);
    u.z = (u32)f2bf(f[4]) | ((u32)f2bf(f[5]) << 16);
    u.w = (u32)f2bf(f[6]) | ((u32)f2bf(f[7]) << 16);
    return u;
}

__device__ __forceinline__ void ph_barrier() {
    asm volatile("" ::: "memory");
    __builtin_amdgcn_s_barrier();
    asm volatile("" ::: "memory");
}

// ---------------------------------------------------------------------------
// Fused prep kernel (round-9): cast x->bf16 + transpose w_attn + transpose
// w_proj + rope table, all independent, one launch. Removes 3 inter-kernel
// graph boundaries (~80-90 us of un-attributed inter-dispatch time in the
// r8 budget audit). Branches are block-uniform (no divergence); inner code
// is verbatim from the four proven kernels.
//   blocks [0, 8192):        cast_bf16          (x -> xb)
//   blocks [8192, 20480):    transpose w_attn   -> waT [6144][2048]
//   blocks [20480, 24576):   transpose w_proj   -> wpT [2048][2048]
//   blocks [24576, 24832):   rope_table         -> ct/st
// ---------------------------------------------------------------------------
__device__ __forceinline__ void transpose_tile(
    const float* __restrict__ in, u16* __restrict__ out, int R, int Cc,
    int bx, int by, float (*tile)[33], int tid)
{
    const int c0 = bx * 32, r0 = by * 32;
    const int tx = tid & 31, ty = tid >> 5;  // ty 0..7
#pragma unroll
    for (int i = 0; i < 32; i += 8)
        tile[ty + i][tx] = in[(size_t)(r0 + ty + i) * Cc + c0 + tx];
    __syncthreads();
#pragma unroll
    for (int i = 0; i < 32; i += 8)
        out[(size_t)(c0 + ty + i) * R + r0 + tx] = f2bf(tile[tx][ty + i]);
}

__global__ __launch_bounds__(256) void prep(
    const float* __restrict__ x,      u16* __restrict__ xb,
    const float* __restrict__ w_attn, u16* __restrict__ waT,
    const float* __restrict__ w_proj, u16* __restrict__ wpT,
    float* __restrict__ ct, float* __restrict__ st)
{
    __shared__ float tile[32][33];
    const int tid = threadIdx.x;
    const int blk = blockIdx.x;

    if (blk < 8192) {
        // ---- cast x fp32 -> bf16 ----
        const int i = blk * 256 + tid;
        float4 v = ((const float4*)x)[i];
        ushort4 o;
        o.x = f2bf(v.x); o.y = f2bf(v.y); o.z = f2bf(v.z); o.w = f2bf(v.w);
        ((ushort4*)xb)[i] = o;
    } else if (blk < 20480) {
        // ---- transpose+cast w_attn [2048][6144] -> waT [6144][2048] ----
        const int b2 = blk - 8192;
        transpose_tile(w_attn, waT, C_DIM, QKV_N, b2 % 192, b2 / 192, tile, tid);
    } else if (blk < 24576) {
        // ---- transpose+cast w_proj [2048][2048] -> wpT [2048][2048] ----
        const int b2 = blk - 20480;
        transpose_tile(w_proj, wpT, C_DIM, C_DIM, b2 & 63, b2 >> 6, tile, tid);
    } else {
        // ---- rope cos/sin table ----
        const int i = (blk - 24576) * 256 + tid;   // t*64 + d2
        const int d2 = i & 63, t = i >> 6;
        const float invf = expf(-(float)d2 * (9.210340371976184f / 64.0f));
        const float fr = (float)t * invf;
        ct[i] = cosf(fr);
        st[i] = sinf(fr);
    }
}

// ---------------------------------------------------------------------------
// 128xBN-tile 8-wave MFMA GEMM, 2 blocks/CU (round-6 proven optimum: QKV
// 94 us @ MfmaUtil 51%). GEMM response surface mapped on all sides of this
// point (256-tile 1-blk: 106; 8-phase fenced: 141; 4-phase: 127; BK=32
// 3-blk: 131) — local optimum; frozen.
// ---------------------------------------------------------------------------
template <int BN, int OUT_BF16>
__global__ __launch_bounds__(512, 4) void gemm_bf16_ov(
    const u16* __restrict__ A,    // [M][K] bf16
    const u16* __restrict__ Bt,   // [N][K] bf16 (B transposed)
    const float* __restrict__ bias,
    void* __restrict__ Cout,      // bf16 [M][N] or fp32 [M][N]
    int M, int N, int K)
{
    constexpr int BI  = BN / 64;         // B stage issues per wave
    constexpr int NTW = BN / 64;         // n-frags per wave
    constexpr int WCOLS = BN / 4;        // cols per wave
    __shared__ alignas(16) char lds[2][16384 + BN * 128];  // [buf][A 16K | B]

    const int tid  = threadIdx.x;
    const int lane = tid & 63;
    const int w    = tid >> 6;      // 0..7
    const int wr   = w >> 2;        // 0..1 (M)
    const int wc   = w & 3;         // 0..3 (N)
    const int l15  = lane & 15;
    const int l4   = lane >> 4;
    const int m0   = blockIdx.y * 128;
    const int n0   = blockIdx.x * BN;
    const int NT   = K >> 6;        // K-tiles of 64

    f32x4 acc[4][NTW] = {};

    const int srow  = w * 16 + (lane >> 3);          // A rows, +i*8 per issue
    const int sslot = (lane & 7) ^ (lane >> 3);      // row&7 == lane>>3
    const size_t aoff = (size_t)(m0 + srow) * K + sslot * 8;
    const int brow_s = w * 8 + (lane >> 3);          // B rows, +i*64 per issue
    const size_t boff = (size_t)(n0 + brow_s) * K + sslot * 8;

    auto stageA = [&](char* buf, int k0) {           // 128 rows, 2 issues
#pragma unroll
        for (int i = 0; i < 2; ++i)
            __builtin_amdgcn_global_load_lds(
                AS1C(A + aoff + (size_t)(i * 8) * K + k0),
                AS3(buf + w * 2048 + i * 1024), 16, 0, 0);
    };
    auto stageB = [&](char* buf, int k0) {           // BN rows, BI issues
#pragma unroll
        for (int i = 0; i < BI; ++i)
            __builtin_amdgcn_global_load_lds(
                AS1C(Bt + boff + (size_t)(i * 64) * K + k0),
                AS3(buf + 16384 + i * 8192 + w * 1024), 16, 0, 0);
    };

    // prologue: B(kt0), A(kt0) -> buf0; B(kt1) -> buf1.
    stageB(lds[0], 0);
    stageA(lds[0], 0);
    stageB(lds[1], 64);
    if (BI == 3) asm volatile("s_waitcnt vmcnt(3)" ::: "memory");
    else         asm volatile("s_waitcnt vmcnt(2)" ::: "memory");
    ph_barrier();

    const int sl0  = (l4 ^ (l15 & 7)) << 4;
    const int sl1  = sl0 ^ 64;
    const int arow = (wr * 64 + l15) * 128;
    const int brow = 16384 + (wc * WCOLS + l15) * 128;

    for (int kt = 0; kt < NT; ++kt) {
        char* cb = lds[kt & 1];
        char* nb = lds[(kt & 1) ^ 1];

        // ---- phase 1: read B(all)+A mt01, stage (kt+1):A, MFMA mt01 ------
        bf16x8 bfr[NTW][2], af[2][2];
#pragma unroll
        for (int nt = 0; nt < NTW; ++nt) {
            bfr[nt][0] = __builtin_bit_cast(bf16x8,
                *(const uint4*)(cb + brow + nt * 2048 + sl0));
            bfr[nt][1] = __builtin_bit_cast(bf16x8,
                *(const uint4*)(cb + brow + nt * 2048 + sl1));
        }
#pragma unroll
        for (int mt = 0; mt < 2; ++mt) {
            af[mt][0] = __builtin_bit_cast(bf16x8,
                *(const uint4*)(cb + arow + mt * 2048 + sl0));
            af[mt][1] = __builtin_bit_cast(bf16x8,
                *(const uint4*)(cb + arow + mt * 2048 + sl1));
        }
        if (kt + 1 < NT) stageA(nb, (kt + 1) << 6);
        __builtin_amdgcn_s_setprio(1);
#pragma unroll
        for (int mt = 0; mt < 2; ++mt)
#pragma unroll
            for (int nt = 0; nt < NTW; ++nt)
#pragma unroll
                for (int kk = 0; kk < 2; ++kk)
                    acc[mt][nt] = __builtin_amdgcn_mfma_f32_16x16x32_bf16(
                        af[mt][kk], bfr[nt][kk], acc[mt][nt], 0, 0, 0);
        __builtin_amdgcn_s_setprio(0);
        ph_barrier();                       // BARRIER_A

        // ---- phase 2: read A mt23, stage (kt+2):B -> cb, MFMA mt23 -------
        bf16x8 ag[2][2];
#pragma unroll
        for (int mt = 0; mt < 2; ++mt) {
            ag[mt][0] = __builtin_bit_cast(bf16x8,
                *(const uint4*)(cb + arow + (2 + mt) * 2048 + sl0));
            ag[mt][1] = __builtin_bit_cast(bf16x8,
                *(const uint4*)(cb + arow + (2 + mt) * 2048 + sl1));
        }
        if (kt + 2 < NT) stageB(cb, (kt + 2) << 6);
        __builtin_amdgcn_s_setprio(1);
#pragma unroll
        for (int mt = 0; mt < 2; ++mt)
#pragma unroll
            for (int nt = 0; nt < NTW; ++nt)
#pragma unroll
                for (int kk = 0; kk < 2; ++kk)
                    acc[mt + 2][nt] = __builtin_amdgcn_mfma_f32_16x16x32_bf16(
                        ag[mt][kk], bfr[nt][kk], acc[mt + 2][nt], 0, 0, 0);
        __builtin_amdgcn_s_setprio(0);
        if (kt < NT - 2) {
            if (BI == 3) asm volatile("s_waitcnt vmcnt(3)" ::: "memory");
            else         asm volatile("s_waitcnt vmcnt(2)" ::: "memory");
        } else {
            asm volatile("s_waitcnt vmcnt(0)" ::: "memory");
        }
        ph_barrier();                       // BARRIER_B
    }

    // epilogue: C/D layout row=l4*4+reg, col=l15
#pragma unroll
    for (int nt = 0; nt < NTW; ++nt) {
        const int colg = n0 + wc * WCOLS + nt * 16 + l15;
        const float bv = bias[colg];
#pragma unroll
        for (int mt = 0; mt < 4; ++mt) {
            const int rowb = m0 + wr * 64 + mt * 16 + l4 * 4;
#pragma unroll
            for (int r = 0; r < 4; ++r) {
                const float v = acc[mt][nt][r] + bv;
                if (OUT_BF16)
                    ((u16*)Cout)[(size_t)(rowb + r) * N + colg] = f2bf(v);
                else
                    ((float*)Cout)[(size_t)(rowb + r) * N + colg] = v;
            }
        }
    }
}

// ---------------------------------------------------------------------------
// Fused RoPE + QKV relayout v3 (round-5 proven).
// ---------------------------------------------------------------------------
__global__ __launch_bounds__(256) void rope_kv(
    const u16* __restrict__ qkv, const float* __restrict__ ct,
    const float* __restrict__ st,
    u16* __restrict__ Qc, u16* __restrict__ Kc, u16* __restrict__ Vt)
{
    __shared__ u16 vtile[128][264];      // 264 = 256 + 8 pad (16B-aligned rows)
    const int tid = threadIdx.x;
    const int blk = blockIdx.x;          // b(4) x h(16) x ttile(4)
    const int tt = blk & 3;
    const int h  = (blk >> 2) & 15;
    const int b  = blk >> 6;
    const int bh = b * 16 + h;

    // ---------------- Q/K: coalesced reads + shfl rope --------------------
    const int c8 = tid & 15;             // 16B chunk within the 128-d head
    const int rg = tid >> 4;             // row within sweep (16 rows/sweep)
    const float sgn = (c8 < 8) ? -1.f : 1.f;

#pragma unroll 4
    for (int s = 0; s < 16; ++s) {
        const int row = s * 16 + rg;     // 0..255
        const int t   = tt * 256 + row;
        const size_t rsrc = (size_t)(b * T_SEQ + t) * QKV_N + h * D_HEAD;
        const size_t rdst = (size_t)(bh * T_SEQ + t) * D_HEAD + c8 * 8;

        // cos/sin for this thread's 8 cols (d2 = (c8&7)*8 + i)
        const float* crow = ct + t * 64 + (c8 & 7) * 8;
        const float* srow = st + t * 64 + (c8 & 7) * 8;
        float cs[8], sn[8];
        *(float4*)(cs)     = *(const float4*)(crow);
        *(float4*)(cs + 4) = *(const float4*)(crow + 4);
        *(float4*)(sn)     = *(const float4*)(srow);
        *(float4*)(sn + 4) = *(const float4*)(srow + 4);

#pragma unroll
        for (int part = 0; part < 2; ++part) {
            uint4 u = *(const uint4*)(qkv + rsrc + part * C_DIM + c8 * 8);
            uint4 pu;
            pu.x = (u32)__shfl_xor((int)u.x, 8, 64);
            pu.y = (u32)__shfl_xor((int)u.y, 8, 64);
            pu.z = (u32)__shfl_xor((int)u.z, 8, 64);
            pu.w = (u32)__shfl_xor((int)u.w, 8, 64);
            float f[8], pf[8], o[8];
            unpack8(u, f); unpack8(pu, pf);
#pragma unroll
            for (int i = 0; i < 8; ++i)
                o[i] = f[i] * cs[i] + sgn * pf[i] * sn[i];
            u16* outp = (part ? Kc : Qc) + rdst;
            *(uint4*)outp = pack8(o);
        }
    }

    // ---------------- V: column stage + coalesced out ---------------------
    const int t = tt * 256 + tid;
    const size_t vsrc = (size_t)(b * T_SEQ + t) * QKV_N + 2 * C_DIM + h * D_HEAD;
#pragma unroll
    for (int c = 0; c < 16; ++c) {
        uint4 v = *(const uint4*)(qkv + vsrc + c * 8);
        u16 e[8];
        e[0] = (u16)(v.x & 0xffff); e[1] = (u16)(v.x >> 16);
        e[2] = (u16)(v.y & 0xffff); e[3] = (u16)(v.y >> 16);
        e[4] = (u16)(v.z & 0xffff); e[5] = (u16)(v.z >> 16);
        e[6] = (u16)(v.w & 0xffff); e[7] = (u16)(v.w >> 16);
#pragma unroll
        for (int j = 0; j < 8; ++j)
            vtile[c * 8 + j][tid] = e[j];
    }
    __syncthreads();

    // coalesced store: 32 lanes cover one row's 256 u16 (512B contiguous)
    const int dl = tid >> 5;             // 0..7: row within pass
    const int jc = (tid & 31) * 8;       // u16 col
    u16* vt = Vt + ((size_t)bh * D_HEAD) * T_SEQ + (size_t)tt * 256;
#pragma unroll
    for (int pass = 0; pass < 16; ++pass) {
        const int d = pass * 8 + dl;
        *(uint4*)(vt + (size_t)d * T_SEQ + jc) = *(const uint4*)&vtile[d][jc];
    }
}

// ---------------------------------------------------------------------------
// MFMA flash attention, 64-row q-tiles (round-6 form: no setprio — r8 A/B
// showed setprio neutral-to-negative here).
// ---------------------------------------------------------------------------
__global__ __launch_bounds__(256) void attn_mfma(
    const u16* __restrict__ Qc,    // [B*H, T, D] roped
    const u16* __restrict__ Kc,    // [B*H, T, D] roped
    const u16* __restrict__ Vt,    // [B*H, D, T]
    u16* __restrict__ y)           // [B, T, C]
{
    __shared__ alignas(16) char KsL[2][16384];   // [cd(16)][row(64)][16B]
    __shared__ alignas(16) char VtsL[2][16384];  // [jc(8)][drow(128)][16B]
    __shared__ alignas(16) char PwL[4][2176];    // per-wave [jc(8)][q(16)][16B]+pad

    const int tid  = threadIdx.x;
    const int lane = tid & 63;
    const int w    = tid >> 6;
    const int l15  = lane & 15;
    const int l4   = lane >> 4;
    const int p    = blockIdx.x;     // 0..7
    const int bh   = blockIdx.y;     // 0..63
    const int h    = bh & 15;
    const int b    = bh >> 4;

    const size_t kbase = (size_t)bh * T_SEQ * D_HEAD;
    const size_t vbase = (size_t)bh * D_HEAD * T_SEQ;
    const float scale = 0.08838834764831845f;   // 1/sqrt(128)
    char* pw = PwL[w];

    for (int half = 0; half < 2; ++half) {
        const int qt = half ? (15 - p) : p;

        // Q fragments (A-layout: m=lane&15, k=(lane>>4)*8+j)
        const int qrow = qt * 64 + w * 16 + l15;
        const u16* qptr = Qc + ((size_t)(bh * T_SEQ + qrow)) * D_HEAD;
        bf16x8 qf[4];
#pragma unroll
        for (int f = 0; f < 4; ++f)
            qf[f] = __builtin_bit_cast(bf16x8, *(const uint4*)(qptr + f * 32 + l4 * 8));

        f32x4 o[8] = {};                 // O[q=l4*4+r][d=db*16+l15]
        float lrow[4] = {};              // per-lane partial denominators

        __syncthreads();   // prior half's readers done before restaging buf 0

        // prologue: stage kt = 0 into buffer 0
        {
            const u16* ksrc = Kc + kbase + (size_t)(0 * 64 + lane) * D_HEAD;
#pragma unroll
            for (int i = 0; i < 4; ++i) {
                const int cd = w * 4 + i;
                __builtin_amdgcn_global_load_lds(AS1C(ksrc + cd * 8),
                                                 AS3(KsL[0] + cd * 1024), 16, 0, 0);
            }
#pragma unroll
            for (int i = 0; i < 4; ++i) {
                const int jc = w + (i >> 1) * 4;
                const int dh = i & 1;
                const u16* vsrc = Vt + vbase + (size_t)(dh * 64 + lane) * T_SEQ
                                  + 0 * 64 + jc * 8;
                __builtin_amdgcn_global_load_lds(AS1C(vsrc),
                                                 AS3(VtsL[0] + jc * 2048 + dh * 1024), 16, 0, 0);
            }
        }

        int buf = 0;
        for (int kt = 0; kt <= qt; ++kt, buf ^= 1) {
            __syncthreads();     // buf visible; buf^1's readers (kt-2) done
            if (kt < qt) {
                const int kn = kt + 1;
                char* kb = KsL[buf ^ 1];
                char* vb = VtsL[buf ^ 1];
                const u16* ksrc = Kc + kbase + (size_t)(kn * 64 + lane) * D_HEAD;
#pragma unroll
                for (int i = 0; i < 4; ++i) {
                    const int cd = w * 4 + i;
                    __builtin_amdgcn_global_load_lds(AS1C(ksrc + cd * 8),
                                                     AS3(kb + cd * 1024), 16, 0, 0);
                }
#pragma unroll
                for (int i = 0; i < 4; ++i) {
                    const int jc = w + (i >> 1) * 4;
                    const int dh = i & 1;
                    const u16* vsrc = Vt + vbase + (size_t)(dh * 64 + lane) * T_SEQ
                                      + kn * 64 + jc * 8;
                    __builtin_amdgcn_global_load_lds(AS1C(vsrc),
                                                     AS3(vb + jc * 2048 + dh * 1024), 16, 0, 0);
                }
            }

            const char* kbuf = KsL[buf];
            const char* vbuf = VtsL[buf];

            // QK^T: 16 MFMAs
            f32x4 sacc[4] = {};
#pragma unroll
            for (int nb = 0; nb < 4; ++nb)
#pragma unroll
                for (int kc = 0; kc < 4; ++kc) {
                    bf16x8 kf = __builtin_bit_cast(bf16x8,
                        *(const uint4*)(kbuf + (kc * 4 + l4) * 1024 + (nb * 16 + l15) * 16));
                    sacc[nb] = __builtin_amdgcn_mfma_f32_16x16x32_bf16(
                        qf[kc], kf, sacc[nb], 0, 0, 0);
                }

            // P = exp(s*scale - 8), causal-masked on diagonal; partial denoms
#pragma unroll
            for (int nb = 0; nb < 4; ++nb)
#pragma unroll
                for (int r = 0; r < 4; ++r) {
                    const bool masked =
                        (kt == qt) && ((nb * 16 + l15) > (w * 16 + l4 * 4 + r));
                    const float e = masked ? 0.f
                        : __expf(sacc[nb][r] * scale - 8.0f);
                    sacc[nb][r] = e;
                    lrow[r] += e;
                }

            // P: C-layout regs -> bf16 -> per-wave LDS in A-layout chunks
#pragma unroll
            for (int nb = 0; nb < 4; ++nb)
#pragma unroll
                for (int r = 0; r < 4; ++r) {
                    const int j = nb * 16 + l15;
                    const int q = l4 * 4 + r;
                    *(u16*)(pw + (j >> 3) * 272 + q * 16 + (j & 7) * 2) =
                        f2bf(sacc[nb][r]);
                }

            // PV: O += P @ V
            bf16x8 pf[2];
#pragma unroll
            for (int kc2 = 0; kc2 < 2; ++kc2)
                pf[kc2] = __builtin_bit_cast(bf16x8,
                    *(const uint4*)(pw + (kc2 * 4 + l4) * 272 + l15 * 16));
#pragma unroll
            for (int db = 0; db < 8; ++db)
#pragma unroll
                for (int kc2 = 0; kc2 < 2; ++kc2) {
                    bf16x8 vf = __builtin_bit_cast(bf16x8,
                        *(const uint4*)(vbuf + (kc2 * 4 + l4) * 2048 + (db * 16 + l15) * 16));
                    o[db] = __builtin_amdgcn_mfma_f32_16x16x32_bf16(
                        pf[kc2], vf, o[db], 0, 0, 0);
                }
        }

        // end-of-row reduce of denominators across the 16 l15 lanes
        float inv[4];
#pragma unroll
        for (int r = 0; r < 4; ++r) {
            float ls = lrow[r];
#pragma unroll
            for (int off = 1; off < 16; off <<= 1)
                ls += __shfl_xor(ls, off, 64);
            inv[r] = 1.f / ls;
        }
#pragma unroll
        for (int db = 0; db < 8; ++db)
#pragma unroll
            for (int r = 0; r < 4; ++r) {
                const int q = qt * 64 + w * 16 + l4 * 4 + r;
                const int d = h * D_HEAD + db * 16 + l15;
                y[(size_t)(b * T_SEQ + q) * C_DIM + d] = f2bf(o[db][r] * inv[r]);
            }
    }
}

// ---------------------------------------------------------------------------
extern "C" void kernel_launch(void* const* d_in, const int* in_sizes, int n_in,
                              void* d_out, int out_size, void* d_ws, size_t ws_size,
                              hipStream_t stream) {
    const float* x      = (const float*)d_in[0];
    const float* w_attn = (const float*)d_in[1];
    const float* b_attn = (const float*)d_in[2];
    const float* w_proj = (const float*)d_in[3];
    const float* b_proj = (const float*)d_in[4];
    float* out = (float*)d_out;

    char* ws = (char*)d_ws;
    u16* xb   = (u16*)(ws);                        // [4096][2048]    16.78 MB
    u16* waT  = (u16*)(ws + 16777216);             // [6144][2048]    25.17 MB
    u16* Qc   = (u16*)(ws);                        // [64][1024][128] 16.78 MB
    u16* Kc   = (u16*)(ws + 16777216);             // [64][1024][128] 16.78 MB
    u16* Vt   = (u16*)(ws + 33554432);             // [64][128][1024] 16.78 MB
    u16* qkvb = (u16*)(ws + 50331648);             // [4096][6144]    50.33 MB
    u16* wpT  = (u16*)(ws + 109051904);            // [2048][2048]     8.39 MB
    u16* yb   = (u16*)(ws + 125829120);            // [4096][2048]    16.78 MB
    float* ct = (float*)(ws + 142606336);          // [1024][64] 256 KB
    float* st = ct + 65536;

    prep<<<24832, 256, 0, stream>>>(x, xb, w_attn, waT, w_proj, wpT, ct, st);

    gemm_bf16_ov<192, 1><<<dim3(QKV_N / 192, BT / 128), 512, 0, stream>>>(
        xb, waT, b_attn, qkvb, BT, QKV_N, C_DIM);

    rope_kv<<<256, 256, 0, stream>>>(qkvb, ct, st, Qc, Kc, Vt);

    attn_mfma<<<dim3(8, 4 * H_NUM), 256, 0, stream>>>(Qc, Kc, Vt, yb);

    gemm_bf16_ov<128, 0><<<dim3(C_DIM / 128, BT / 128), 512, 0, stream>>>(
        yb, wpT, b_proj, out, BT, C_DIM, C_DIM);
}